// Round 17
// baseline (298.308 us; speedup 1.0000x reference)
//
#include <hip/hip_runtime.h>

typedef unsigned short ushort_t;
typedef __attribute__((ext_vector_type(8))) short bf16x8;
typedef __attribute__((ext_vector_type(4))) float f32x4;
typedef __attribute__((ext_vector_type(16))) float f32x16;
typedef __attribute__((ext_vector_type(4))) int i32x4;
typedef __attribute__((ext_vector_type(2))) unsigned int u32x2;

#define QSCALE 0.1803368801111204f  /* (1/8) * log2(e): softmax in log2 domain */

__device__ inline ushort_t f2bf(float f) {
    unsigned int u = __float_as_uint(f);
    unsigned int r = (u + 0x7FFFu + ((u >> 16) & 1u)) >> 16;
    return (ushort_t)r;
}
// packed bf16 convert (VERIFIED round 7): dst = {lo: bf16(x), hi: bf16(y)}
__device__ inline unsigned pkbf(float x, float y) {
    unsigned d;
    asm("v_cvt_pk_bf16_f32 %0, %1, %2" : "=v"(d) : "v"(x), "v"(y));
    return d;
}
// single-instruction 2^x (VERIFIED round 11)
__device__ inline float vexp2(float x) {
    float r;
    asm("v_exp_f32 %0, %1" : "=v"(r) : "v"(x));
    return r;
}
__device__ inline bf16x8 frag_from(unsigned a, unsigned b, unsigned c, unsigned d) {
    union { i32x4 i; bf16x8 v; } u;
    u.i[0] = (int)a; u.i[1] = (int)b; u.i[2] = (int)c; u.i[3] = (int)d;
    return u.v;
}

// P-fragment builder (movement VERIFIED r4; cvt_pk pack VERIFIED r7):
// lane (li,hi) holds P[q=li][kv_local=(r&3)+8*(r>>2)+4*hi] in x0..x7.
// Produces B-frag: B[k=hi*8+j][col=li].
__device__ inline bf16x8 mkfrag(float x0, float x1, float x2, float x3,
                                float x4, float x5, float x6, float x7, int hi) {
    unsigned A_ = pkbf(x0, x1), B_ = pkbf(x2, x3), C_ = pkbf(x4, x5), D_ = pkbf(x6, x7);
    unsigned Ax = (unsigned)__shfl_xor((int)A_, 32);
    unsigned Bx = (unsigned)__shfl_xor((int)B_, 32);
    unsigned Cx = (unsigned)__shfl_xor((int)C_, 32);
    unsigned Dx = (unsigned)__shfl_xor((int)D_, 32);
    return frag_from(hi ? Cx : A_, hi ? Dx : B_, hi ? C_ : Ax, hi ? D_ : Bx);
}

// ------------- transpose + cast all 4 weights: W[K,N] f32 -> Wt[N,K] bf16 ----
__global__ __launch_bounds__(256) void transpose_cast4(
    const float* __restrict__ W0, const float* __restrict__ W1,
    const float* __restrict__ W2, const float* __restrict__ W3,
    ushort_t* __restrict__ T0, ushort_t* __restrict__ T1,
    ushort_t* __restrict__ T2, ushort_t* __restrict__ T3) {
    __shared__ float tile[32][33];
    const int which = blockIdx.x >> 10;
    const float* W = which == 0 ? W0 : which == 1 ? W1 : which == 2 ? W2 : W3;
    ushort_t* Wt = which == 0 ? T0 : which == 1 ? T1 : which == 2 ? T2 : T3;
    const int bidx = blockIdx.x & 1023;
    const int bx = bidx & 31, by = bidx >> 5;
    const int n0 = bx * 32, k0 = by * 32;
    const int tx = threadIdx.x & 31, ty = threadIdx.x >> 5;
#pragma unroll
    for (int i = 0; i < 4; ++i) {
        int r = ty + i * 8;
        tile[r][tx] = W[(k0 + r) * 1024 + n0 + tx];
    }
    __syncthreads();
#pragma unroll
    for (int i = 0; i < 4; ++i) {
        int r = ty + i * 8;
        Wt[(n0 + r) * 1024 + k0 + tx] = f2bf(tile[tx][r]);
    }
}

// ---------------- GEMM: C[M=8192, N=1024] = A[M,1024] @ Wt[N,1024]^T + bias ---
// BM=128 x BN=256 tile (A re-read passes 8->4: A-traffic bound, not MFMA).
// 512 threads, 8 waves (2x4); per-wave 64x64 sub-tile, acc[4][4] (unchanged).
// Reg-staged A and B into padded-72 LDS (conflict-free reads, r10-verified).
// OMODE 0: bf16 split-heads [B,H,S,D] (scaled). OMODE 1: f32 [M,N].
// OMODE 2: bf16 transposed split-heads [B,H,D,S] (direct Vt).
template <int AF32, int OMODE>
__global__ __launch_bounds__(512) void gemm_bt(const void* __restrict__ Ap,
                                               const ushort_t* __restrict__ Bt,
                                               const float* __restrict__ bias,
                                               void* __restrict__ out, float scale) {
    __shared__ alignas(16) ushort_t As[128 * 72];
    __shared__ alignas(16) ushort_t Bs[256 * 72];
    const int t = threadIdx.x;
    const int lane = t & 63, w = t >> 6;       // w 0..7
    const int q = lane & 15, g = lane >> 4;
    const int wr = w >> 2, wc = w & 3;         // 2 x 4 wave grid
    const int bm = blockIdx.x & 63, bn = blockIdx.x >> 6;   // bn 0..3
    const int m0 = bm * 128, n0 = bn * 256;

    f32x4 acc[4][4];
#pragma unroll
    for (int i = 0; i < 4; ++i)
#pragma unroll
        for (int j = 0; j < 4; ++j) acc[i][j] = (f32x4){0.f, 0.f, 0.f, 0.f};

    for (int k0 = 0; k0 < 1024; k0 += 64) {
        __syncthreads();
        // --- A tile 128x64: 512 thr x 2 iters x 8 elems ---
#pragma unroll
        for (int it = 0; it < 2; ++it) {
            int tt = t + it * 512;
            int row = tt >> 3;
            int col = (tt & 7) * 8;
            if (AF32) {
                const float* A = (const float*)Ap;
                float4 v0 = *(const float4*)&A[(size_t)(m0 + row) * 1024 + k0 + col];
                float4 v1 = *(const float4*)&A[(size_t)(m0 + row) * 1024 + k0 + col + 4];
                *(bf16x8*)&As[row * 72 + col] =
                    frag_from(pkbf(v0.x, v0.y), pkbf(v0.z, v0.w),
                              pkbf(v1.x, v1.y), pkbf(v1.z, v1.w));
            } else {
                const ushort_t* A = (const ushort_t*)Ap;
                *(bf16x8*)&As[row * 72 + col] =
                    *(const bf16x8*)&A[(size_t)(m0 + row) * 1024 + k0 + col];
            }
        }
        // --- B tile 256x64: 512 thr x 4 iters x 8 elems ---
#pragma unroll
        for (int it = 0; it < 4; ++it) {
            int tt = t + it * 512;
            int row = tt >> 3;
            int col = (tt & 7) * 8;
            *(bf16x8*)&Bs[row * 72 + col] =
                *(const bf16x8*)&Bt[(size_t)(n0 + row) * 1024 + k0 + col];
        }
        __syncthreads();
#pragma unroll
        for (int kt = 0; kt < 2; ++kt) {
            bf16x8 af[4], bfr[4];
#pragma unroll
            for (int mt = 0; mt < 4; ++mt)
                af[mt] = *(const bf16x8*)&As[(wr * 64 + mt * 16 + q) * 72 + kt * 32 + g * 8];
#pragma unroll
            for (int nt = 0; nt < 4; ++nt)
                bfr[nt] = *(const bf16x8*)&Bs[(wc * 64 + nt * 16 + q) * 72 + kt * 32 + g * 8];
#pragma unroll
            for (int mt = 0; mt < 4; ++mt)
#pragma unroll
                for (int nt = 0; nt < 4; ++nt)
                    acc[mt][nt] = __builtin_amdgcn_mfma_f32_16x16x32_bf16(
                        af[mt], bfr[nt], acc[mt][nt], 0, 0, 0);
        }
    }

#pragma unroll
    for (int mt = 0; mt < 4; ++mt) {
#pragma unroll
        for (int nt = 0; nt < 4; ++nt) {
            const int col = n0 + wc * 64 + nt * 16 + q;
            if (OMODE == 2) {
                const int grow0 = m0 + wr * 64 + mt * 16 + g * 4;  // mult of 4
                const int b = grow0 >> 11, si = grow0 & 2047;
                const int h = col >> 6, d = col & 63;
                float v0 = (acc[mt][nt][0] + bias[col]) * scale;
                float v1 = (acc[mt][nt][1] + bias[col]) * scale;
                float v2 = (acc[mt][nt][2] + bias[col]) * scale;
                float v3 = (acc[mt][nt][3] + bias[col]) * scale;
                u32x2 uv;
                uv[0] = pkbf(v0, v1);
                uv[1] = pkbf(v2, v3);
                *(u32x2*)&((ushort_t*)out)[((size_t)((b * 16 + h) * 64 + d)) * 2048 + si] = uv;
            } else {
#pragma unroll
                for (int r = 0; r < 4; ++r) {
                    int grow = m0 + wr * 64 + mt * 16 + g * 4 + r;
                    float v = acc[mt][nt][r] + bias[col];
                    if (OMODE == 0) {
                        int b = grow >> 11, s = grow & 2047;
                        int h = col >> 6, d = col & 63;
                        ((ushort_t*)out)[(((size_t)(b * 16 + h) * 2048 + s) * 64) + d] =
                            f2bf(v * scale);
                    } else {
                        ((float*)out)[(size_t)grow * 1024 + col] = v;
                    }
                }
            }
        }
    }
}

// ---------------- flash attention, 32x32 swapped-operand, reg-staged K/V -----
// r12/r16-VERIFIED best (103.7-104.3 us): 8 waves x 32 q = 256 q/block;
// grid 512; reg-staged double-buffered K/V, vexp2, VALU sum tree.
__global__ __launch_bounds__(512, 4) void attn_kernel(const ushort_t* __restrict__ Qp,
                                                      const ushort_t* __restrict__ Kp,
                                                      const ushort_t* __restrict__ Vtp,
                                                      ushort_t* __restrict__ Oa) {
    __shared__ alignas(16) ushort_t Ks[2][4096];  // [64 kv][64 d], rows XOR-swizzled
    __shared__ alignas(16) ushort_t Vs[2][4096];  // [64 d][64 kv], rows XOR-swizzled

    const int t = threadIdx.x, lane = t & 63, w = t >> 6;  // w 0..7
    const int li = lane & 31, hi = lane >> 5;
    // XCD-contiguous remap: 512 = 8 xcd * 64 (bijective); pair = bid>>3
    const int bid = (blockIdx.x & 7) * 64 + (blockIdx.x >> 3);
    const int pair = bid >> 3;
    const int qbase = (bid & 7) * 256 + w * 32;

    const ushort_t* Qh = Qp + (size_t)pair * 2048 * 64;
    const ushort_t* Kh = Kp + (size_t)pair * 2048 * 64;
    const ushort_t* Vh = Vtp + (size_t)pair * 64 * 2048;

    // Q B-frags: B[k][col=li] = Q[qbase+li][k], k = ks*16 + hi*8 + j
    bf16x8 qf[4];
#pragma unroll
    for (int ks = 0; ks < 4; ++ks)
        qf[ks] = *(const bf16x8*)&Qh[(size_t)(qbase + li) * 64 + ks * 16 + hi * 8];

    const f32x16 z16 = {0.f,0.f,0.f,0.f,0.f,0.f,0.f,0.f,0.f,0.f,0.f,0.f,0.f,0.f,0.f,0.f};
    f32x16 o0 = z16, o1 = z16;
    float m_ = -1e30f, l_ = 0.f;

    // staging: thread t (0..511) covers row r8 = t>>3 (0..63), slot t&7;
    // writes LDS 16B chunk at slot (t&7)^(r8&7). Read side applies same XOR.
    const int r8 = t >> 3;
    const int lcol = (t & 7) * 16;
    const int swoff = (r8 * 128) + (lcol ^ ((r8 & 7) << 4));
    const char* kp0 = (const char*)Kh + (size_t)r8 * 128 + lcol;   // +8192/tile
    const char* vp0 = (const char*)Vh + (size_t)r8 * 4096 + lcol;  // +128/tile
    char* KsB = (char*)Ks;
    char* VsB = (char*)Vs;
    const int sw = (li & 7) << 4;

    i32x4 gk0 = *(const i32x4*)(kp0);
    i32x4 gv0 = *(const i32x4*)(vp0);
    // prologue: stage tile 0 into buf0, load tile 1 into regs
    *(i32x4*)(KsB + swoff) = gk0;
    *(i32x4*)(VsB + swoff) = gv0;
    gk0 = *(const i32x4*)(kp0 + 8192);
    gv0 = *(const i32x4*)(vp0 + 128);
    __syncthreads();

    for (int it = 0; it < 32; ++it) {
        const int cur = it & 1;
        // stage tile it+1 into buf cur^1 (free: all waves left it after barrier)
        if (it < 31) {
            const int nb = (cur ^ 1) * 8192;
            *(i32x4*)(KsB + nb + swoff) = gk0;
            *(i32x4*)(VsB + nb + swoff) = gv0;
        }
        if (it < 30) {  // issue tile it+2 loads; latency hides under compute
            gk0 = *(const i32x4*)(kp0 + (size_t)(it + 2) * 8192);
            gv0 = *(const i32x4*)(vp0 + (size_t)(it + 2) * 128);
        }

        const char* kb = KsB + cur * 8192;
        const char* vb = VsB + cur * 8192;

        // --- QK^T: S^T[kv][q], two 32-kv halves ---
        f32x16 s0 = z16, s1 = z16;
        __builtin_amdgcn_s_setprio(1);
#pragma unroll
        for (int ks = 0; ks < 4; ++ks) {
            const int b = ks * 32 + hi * 16;
            bf16x8 k0 = *(const bf16x8*)(kb + li * 128 + (b ^ sw));
            bf16x8 k1 = *(const bf16x8*)(kb + (32 + li) * 128 + (b ^ sw));
            s0 = __builtin_amdgcn_mfma_f32_32x32x16_bf16(k0, qf[ks], s0, 0, 0, 0);
            s1 = __builtin_amdgcn_mfma_f32_32x32x16_bf16(k1, qf[ks], s1, 0, 0, 0);
        }
        __builtin_amdgcn_s_setprio(0);

        // --- online softmax (log2 domain), lane-local rows, tree max ---
        float mx[8];
#pragma unroll
        for (int j = 0; j < 8; ++j)
            mx[j] = fmaxf(fmaxf(s0[j], s0[j + 8]), fmaxf(s1[j], s1[j + 8]));
        float m01 = fmaxf(mx[0], mx[1]), m23 = fmaxf(mx[2], mx[3]);
        float m45 = fmaxf(mx[4], mx[5]), m67 = fmaxf(mx[6], mx[7]);
        float tm = fmaxf(fmaxf(m01, m23), fmaxf(m45, m67));
        tm = fmaxf(tm, __shfl_xor(tm, 32));
        if (__any(tm > m_ + 8.f)) {  // defer-max (T13)
            float mn = fmaxf(m_, tm);
            float corr = vexp2(m_ - mn);
#pragma unroll
            for (int r = 0; r < 16; ++r) { o0[r] *= corr; o1[r] *= corr; }
            l_ *= corr;
            m_ = mn;
        }
#pragma unroll
        for (int r = 0; r < 16; ++r) s0[r] = vexp2(s0[r] - m_);
#pragma unroll
        for (int r = 0; r < 16; ++r) s1[r] = vexp2(s1[r] - m_);
        // --- row sum (r6-verified VALU tree) ---
        float su[8];
#pragma unroll
        for (int j = 0; j < 8; ++j)
            su[j] = (s0[j] + s0[j + 8]) + (s1[j] + s1[j + 8]);
        float s01 = su[0] + su[1], s23 = su[2] + su[3];
        float s45 = su[4] + su[5], s67 = su[6] + su[7];
        float sum = (s01 + s23) + (s45 + s67);
        sum += __shfl_xor(sum, 32);
        l_ += sum;

        // --- pack P -> 4 B-frags (verified path) ---
        bf16x8 pf[4];
        pf[0] = mkfrag(s0[0], s0[1], s0[2], s0[3], s0[4], s0[5], s0[6], s0[7], hi);
        pf[1] = mkfrag(s0[8], s0[9], s0[10], s0[11], s0[12], s0[13], s0[14], s0[15], hi);
        pf[2] = mkfrag(s1[0], s1[1], s1[2], s1[3], s1[4], s1[5], s1[6], s1[7], hi);
        pf[3] = mkfrag(s1[8], s1[9], s1[10], s1[11], s1[12], s1[13], s1[14], s1[15], hi);

        // --- PV: O^T[d][q] += V^T . P^T ---
        __builtin_amdgcn_s_setprio(1);
#pragma unroll
        for (int ks = 0; ks < 4; ++ks) {
            const int b = ks * 32 + hi * 16;
            bf16x8 v0 = *(const bf16x8*)(vb + li * 128 + (b ^ sw));
            bf16x8 v1 = *(const bf16x8*)(vb + (32 + li) * 128 + (b ^ sw));
            o0 = __builtin_amdgcn_mfma_f32_32x32x16_bf16(v0, pf[ks], o0, 0, 0, 0);
            o1 = __builtin_amdgcn_mfma_f32_32x32x16_bf16(v1, pf[ks], o1, 0, 0, 0);
        }
        __builtin_amdgcn_s_setprio(0);

        __syncthreads();  // writes to cur^1 visible; everyone done reading cur
    }

    // --- epilogue: lane (li,hi) owns q=qbase+li; o_dt[r] = O^T[d][q],
    //     d = (r&3) + 8*(r>>2) + 4*hi + 32*dt.  l = l_. ---
    const float rl = 1.0f / l_;
    const int b = pair >> 4, hh = pair & 15;
    const int s = qbase + li;
    const size_t rowbase = ((size_t)(b * 2048 + s)) * 1024 + hh * 64;
#pragma unroll
    for (int dt = 0; dt < 2; ++dt) {
#pragma unroll
        for (int rq = 0; rq < 4; ++rq) {
            float v0 = (dt ? o1[rq * 4 + 0] : o0[rq * 4 + 0]) * rl;
            float v1 = (dt ? o1[rq * 4 + 1] : o0[rq * 4 + 1]) * rl;
            float v2 = (dt ? o1[rq * 4 + 2] : o0[rq * 4 + 2]) * rl;
            float v3 = (dt ? o1[rq * 4 + 3] : o0[rq * 4 + 3]) * rl;
            u32x2 uv;
            uv[0] = pkbf(v0, v1);
            uv[1] = pkbf(v2, v3);
            *(u32x2*)&Oa[rowbase + dt * 32 + rq * 8 + hi * 4] = uv;
        }
    }
}

extern "C" void kernel_launch(void* const* d_in, const int* in_sizes, int n_in,
                              void* d_out, int out_size, void* d_ws, size_t ws_size,
                              hipStream_t stream) {
    const float* query = (const float*)d_in[0];
    const float* key_ = (const float*)d_in[1];
    const float* value = (const float*)d_in[2];
    const float* Wq = (const float*)d_in[3];
    const float* bq = (const float*)d_in[4];
    const float* Wk = (const float*)d_in[5];
    const float* bk = (const float*)d_in[6];
    const float* Wv = (const float*)d_in[7];
    const float* bv = (const float*)d_in[8];
    const float* Wo = (const float*)d_in[9];
    const float* bo = (const float*)d_in[10];
    float* out = (float*)d_out;

    char* ws = (char*)d_ws;
    ushort_t* Wqt = (ushort_t*)(ws + 0);
    ushort_t* Wkt = (ushort_t*)(ws + 2097152);
    ushort_t* Wvt = (ushort_t*)(ws + 4194304);
    ushort_t* Wot = (ushort_t*)(ws + 6291456);
    ushort_t* Qp = (ushort_t*)(ws + 8388608);
    ushort_t* Kp = (ushort_t*)(ws + 25165824);
    ushort_t* Vt = (ushort_t*)(ws + 58720256);
    ushort_t* Oa = (ushort_t*)(ws + 41943040);

    transpose_cast4<<<4096, 256, 0, stream>>>(Wq, Wk, Wv, Wo, Wqt, Wkt, Wvt, Wot);

    gemm_bt<1, 0><<<256, 512, 0, stream>>>((const void*)query, Wqt, bq, (void*)Qp, QSCALE);
    gemm_bt<1, 0><<<256, 512, 0, stream>>>((const void*)key_, Wkt, bk, (void*)Kp, 1.0f);
    gemm_bt<1, 2><<<256, 512, 0, stream>>>((const void*)value, Wvt, bv, (void*)Vt, 1.0f);

    attn_kernel<<<512, 512, 0, stream>>>(Qp, Kp, Vt, Oa);

    gemm_bt<0, 1><<<256, 512, 0, stream>>>((const void*)Oa, Wot, bo, (void*)out, 1.0f);
}

// Round 18
// 219.280 us; speedup vs baseline: 1.3604x; 1.3604x over previous
//
#include <hip/hip_runtime.h>

typedef unsigned short ushort_t;
typedef __attribute__((ext_vector_type(8))) short bf16x8;
typedef __attribute__((ext_vector_type(4))) float f32x4;
typedef __attribute__((ext_vector_type(16))) float f32x16;
typedef __attribute__((ext_vector_type(4))) int i32x4;
typedef __attribute__((ext_vector_type(2))) unsigned int u32x2;

#define QSCALE 0.1803368801111204f  /* (1/8) * log2(e): softmax in log2 domain */

__device__ inline ushort_t f2bf(float f) {
    unsigned int u = __float_as_uint(f);
    unsigned int r = (u + 0x7FFFu + ((u >> 16) & 1u)) >> 16;
    return (ushort_t)r;
}
// packed bf16 convert (VERIFIED round 7): dst = {lo: bf16(x), hi: bf16(y)}
__device__ inline unsigned pkbf(float x, float y) {
    unsigned d;
    asm("v_cvt_pk_bf16_f32 %0, %1, %2" : "=v"(d) : "v"(x), "v"(y));
    return d;
}
// single-instruction 2^x (VERIFIED round 11)
__device__ inline float vexp2(float x) {
    float r;
    asm("v_exp_f32 %0, %1" : "=v"(r) : "v"(x));
    return r;
}
__device__ inline bf16x8 frag_from(unsigned a, unsigned b, unsigned c, unsigned d) {
    union { i32x4 i; bf16x8 v; } u;
    u.i[0] = (int)a; u.i[1] = (int)b; u.i[2] = (int)c; u.i[3] = (int)d;
    return u.v;
}

// P-fragment builder (movement VERIFIED r4; cvt_pk pack VERIFIED r7):
// lane (li,hi) holds P[q=li][kv_local=(r&3)+8*(r>>2)+4*hi] in x0..x7.
// Produces B-frag: B[k=hi*8+j][col=li].
__device__ inline bf16x8 mkfrag(float x0, float x1, float x2, float x3,
                                float x4, float x5, float x6, float x7, int hi) {
    unsigned A_ = pkbf(x0, x1), B_ = pkbf(x2, x3), C_ = pkbf(x4, x5), D_ = pkbf(x6, x7);
    unsigned Ax = (unsigned)__shfl_xor((int)A_, 32);
    unsigned Bx = (unsigned)__shfl_xor((int)B_, 32);
    unsigned Cx = (unsigned)__shfl_xor((int)C_, 32);
    unsigned Dx = (unsigned)__shfl_xor((int)D_, 32);
    return frag_from(hi ? Cx : A_, hi ? Dx : B_, hi ? C_ : Ax, hi ? D_ : Bx);
}

// ------------- transpose + cast all 4 weights: W[K,N] f32 -> Wt[N,K] bf16 ----
__global__ __launch_bounds__(256) void transpose_cast4(
    const float* __restrict__ W0, const float* __restrict__ W1,
    const float* __restrict__ W2, const float* __restrict__ W3,
    ushort_t* __restrict__ T0, ushort_t* __restrict__ T1,
    ushort_t* __restrict__ T2, ushort_t* __restrict__ T3) {
    __shared__ float tile[32][33];
    const int which = blockIdx.x >> 10;
    const float* W = which == 0 ? W0 : which == 1 ? W1 : which == 2 ? W2 : W3;
    ushort_t* Wt = which == 0 ? T0 : which == 1 ? T1 : which == 2 ? T2 : T3;
    const int bidx = blockIdx.x & 1023;
    const int bx = bidx & 31, by = bidx >> 5;
    const int n0 = bx * 32, k0 = by * 32;
    const int tx = threadIdx.x & 31, ty = threadIdx.x >> 5;
#pragma unroll
    for (int i = 0; i < 4; ++i) {
        int r = ty + i * 8;
        tile[r][tx] = W[(k0 + r) * 1024 + n0 + tx];
    }
    __syncthreads();
#pragma unroll
    for (int i = 0; i < 4; ++i) {
        int r = ty + i * 8;
        Wt[(n0 + r) * 1024 + k0 + tx] = f2bf(tile[tx][r]);
    }
}

// ------------- merged QKV projection GEMM (r16-verified body) ----------------
// 1536 blocks: which = bid>>9 selects {query->Qp(OMODE0,QSCALE), key->Kp(OMODE0),
// value->Vt(OMODE2 transposed split-heads)}. 128x128 tile, 256 thr, padded-72.
__global__ __launch_bounds__(256) void gemm_qkv(
    const float* __restrict__ Aq, const float* __restrict__ Ak,
    const float* __restrict__ Av,
    const ushort_t* __restrict__ Wq, const ushort_t* __restrict__ Wk,
    const ushort_t* __restrict__ Wv,
    const float* __restrict__ bq, const float* __restrict__ bk,
    const float* __restrict__ bv,
    ushort_t* __restrict__ Qp, ushort_t* __restrict__ Kp,
    ushort_t* __restrict__ Vt) {
    __shared__ alignas(16) ushort_t As[128 * 72];
    __shared__ alignas(16) ushort_t Bs[128 * 72];
    const int which = blockIdx.x >> 9;
    const int bid = blockIdx.x & 511;
    const float* A = which == 0 ? Aq : which == 1 ? Ak : Av;
    const ushort_t* Bt = which == 0 ? Wq : which == 1 ? Wk : Wv;
    const float* bias = which == 0 ? bq : which == 1 ? bk : bv;
    const float scale = which == 0 ? QSCALE : 1.0f;

    const int t = threadIdx.x;
    const int lane = t & 63, w = t >> 6;
    const int q = lane & 15, g = lane >> 4;
    const int wr = w >> 1, wc = w & 1;
    const int bm = bid & 63, bn = bid >> 6;
    const int m0 = bm * 128, n0 = bn * 128;

    f32x4 acc[4][4];
#pragma unroll
    for (int i = 0; i < 4; ++i)
#pragma unroll
        for (int j = 0; j < 4; ++j) acc[i][j] = (f32x4){0.f, 0.f, 0.f, 0.f};

    for (int k0 = 0; k0 < 1024; k0 += 64) {
        __syncthreads();
#pragma unroll
        for (int it = 0; it < 4; ++it) {
            int tt = t + it * 256;
            int row = tt >> 3;
            int col = (tt & 7) * 8;
            float4 v0 = *(const float4*)&A[(size_t)(m0 + row) * 1024 + k0 + col];
            float4 v1 = *(const float4*)&A[(size_t)(m0 + row) * 1024 + k0 + col + 4];
            *(bf16x8*)&As[row * 72 + col] =
                frag_from(pkbf(v0.x, v0.y), pkbf(v0.z, v0.w),
                          pkbf(v1.x, v1.y), pkbf(v1.z, v1.w));
            *(bf16x8*)&Bs[row * 72 + col] =
                *(const bf16x8*)&Bt[(size_t)(n0 + row) * 1024 + k0 + col];
        }
        __syncthreads();
#pragma unroll
        for (int kt = 0; kt < 2; ++kt) {
            bf16x8 af[4], bfr[4];
#pragma unroll
            for (int mt = 0; mt < 4; ++mt)
                af[mt] = *(const bf16x8*)&As[(wr * 64 + mt * 16 + q) * 72 + kt * 32 + g * 8];
#pragma unroll
            for (int nt = 0; nt < 4; ++nt)
                bfr[nt] = *(const bf16x8*)&Bs[(wc * 64 + nt * 16 + q) * 72 + kt * 32 + g * 8];
#pragma unroll
            for (int mt = 0; mt < 4; ++mt)
#pragma unroll
                for (int nt = 0; nt < 4; ++nt)
                    acc[mt][nt] = __builtin_amdgcn_mfma_f32_16x16x32_bf16(
                        af[mt], bfr[nt], acc[mt][nt], 0, 0, 0);
        }
    }

#pragma unroll
    for (int mt = 0; mt < 4; ++mt) {
#pragma unroll
        for (int nt = 0; nt < 4; ++nt) {
            const int col = n0 + wc * 64 + nt * 16 + q;
            if (which == 2) {  // OMODE 2: Vt[B,H,D,S], 4 consecutive s -> 8B store
                const int grow0 = m0 + wr * 64 + mt * 16 + g * 4;
                const int b = grow0 >> 11, si = grow0 & 2047;
                const int h = col >> 6, d = col & 63;
                float v0 = acc[mt][nt][0] + bias[col];
                float v1 = acc[mt][nt][1] + bias[col];
                float v2 = acc[mt][nt][2] + bias[col];
                float v3 = acc[mt][nt][3] + bias[col];
                u32x2 uv;
                uv[0] = pkbf(v0, v1);
                uv[1] = pkbf(v2, v3);
                *(u32x2*)&Vt[((size_t)((b * 16 + h) * 64 + d)) * 2048 + si] = uv;
            } else {  // OMODE 0: [B,H,S,D] bf16, scaled
                ushort_t* outp = which == 0 ? Qp : Kp;
#pragma unroll
                for (int r = 0; r < 4; ++r) {
                    int grow = m0 + wr * 64 + mt * 16 + g * 4 + r;
                    float v = acc[mt][nt][r] + bias[col];
                    int b = grow >> 11, s = grow & 2047;
                    int h = col >> 6, d = col & 63;
                    outp[(((size_t)(b * 16 + h) * 2048 + s) * 64) + d] = f2bf(v * scale);
                }
            }
        }
    }
}

// ---------------- final GEMM: out[M,1024] f32 = Oa[M,1024]bf16 @ Wot^T + bo --
__global__ __launch_bounds__(256) void gemm_out(const ushort_t* __restrict__ Ap,
                                                const ushort_t* __restrict__ Bt,
                                                const float* __restrict__ bias,
                                                float* __restrict__ out) {
    __shared__ alignas(16) ushort_t As[128 * 72];
    __shared__ alignas(16) ushort_t Bs[128 * 72];
    const int t = threadIdx.x;
    const int lane = t & 63, w = t >> 6;
    const int q = lane & 15, g = lane >> 4;
    const int wr = w >> 1, wc = w & 1;
    const int bm = blockIdx.x & 63, bn = blockIdx.x >> 6;
    const int m0 = bm * 128, n0 = bn * 128;

    f32x4 acc[4][4];
#pragma unroll
    for (int i = 0; i < 4; ++i)
#pragma unroll
        for (int j = 0; j < 4; ++j) acc[i][j] = (f32x4){0.f, 0.f, 0.f, 0.f};

    for (int k0 = 0; k0 < 1024; k0 += 64) {
        __syncthreads();
#pragma unroll
        for (int it = 0; it < 4; ++it) {
            int tt = t + it * 256;
            int row = tt >> 3;
            int col = (tt & 7) * 8;
            *(bf16x8*)&As[row * 72 + col] =
                *(const bf16x8*)&Ap[(size_t)(m0 + row) * 1024 + k0 + col];
            *(bf16x8*)&Bs[row * 72 + col] =
                *(const bf16x8*)&Bt[(size_t)(n0 + row) * 1024 + k0 + col];
        }
        __syncthreads();
#pragma unroll
        for (int kt = 0; kt < 2; ++kt) {
            bf16x8 af[4], bfr[4];
#pragma unroll
            for (int mt = 0; mt < 4; ++mt)
                af[mt] = *(const bf16x8*)&As[(wr * 64 + mt * 16 + q) * 72 + kt * 32 + g * 8];
#pragma unroll
            for (int nt = 0; nt < 4; ++nt)
                bfr[nt] = *(const bf16x8*)&Bs[(wc * 64 + nt * 16 + q) * 72 + kt * 32 + g * 8];
#pragma unroll
            for (int mt = 0; mt < 4; ++mt)
#pragma unroll
                for (int nt = 0; nt < 4; ++nt)
                    acc[mt][nt] = __builtin_amdgcn_mfma_f32_16x16x32_bf16(
                        af[mt], bfr[nt], acc[mt][nt], 0, 0, 0);
        }
    }

#pragma unroll
    for (int mt = 0; mt < 4; ++mt) {
#pragma unroll
        for (int nt = 0; nt < 4; ++nt) {
            const int col = n0 + wc * 64 + nt * 16 + q;
#pragma unroll
            for (int r = 0; r < 4; ++r) {
                int grow = m0 + wr * 64 + mt * 16 + g * 4 + r;
                out[(size_t)grow * 1024 + col] = acc[mt][nt][r] + bias[col];
            }
        }
    }
}

// ---------------- flash attention, 32x32 swapped-operand, reg-staged K/V -----
// r12/r16-VERIFIED best (103.7-104.3 us): 8 waves x 32 q = 256 q/block;
// grid 512; reg-staged double-buffered K/V, vexp2, VALU sum tree.
__global__ __launch_bounds__(512, 4) void attn_kernel(const ushort_t* __restrict__ Qp,
                                                      const ushort_t* __restrict__ Kp,
                                                      const ushort_t* __restrict__ Vtp,
                                                      ushort_t* __restrict__ Oa) {
    __shared__ alignas(16) ushort_t Ks[2][4096];  // [64 kv][64 d], rows XOR-swizzled
    __shared__ alignas(16) ushort_t Vs[2][4096];  // [64 d][64 kv], rows XOR-swizzled

    const int t = threadIdx.x, lane = t & 63, w = t >> 6;  // w 0..7
    const int li = lane & 31, hi = lane >> 5;
    // XCD-contiguous remap: 512 = 8 xcd * 64 (bijective); pair = bid>>3
    const int bid = (blockIdx.x & 7) * 64 + (blockIdx.x >> 3);
    const int pair = bid >> 3;
    const int qbase = (bid & 7) * 256 + w * 32;

    const ushort_t* Qh = Qp + (size_t)pair * 2048 * 64;
    const ushort_t* Kh = Kp + (size_t)pair * 2048 * 64;
    const ushort_t* Vh = Vtp + (size_t)pair * 64 * 2048;

    // Q B-frags: B[k][col=li] = Q[qbase+li][k], k = ks*16 + hi*8 + j
    bf16x8 qf[4];
#pragma unroll
    for (int ks = 0; ks < 4; ++ks)
        qf[ks] = *(const bf16x8*)&Qh[(size_t)(qbase + li) * 64 + ks * 16 + hi * 8];

    const f32x16 z16 = {0.f,0.f,0.f,0.f,0.f,0.f,0.f,0.f,0.f,0.f,0.f,0.f,0.f,0.f,0.f,0.f};
    f32x16 o0 = z16, o1 = z16;
    float m_ = -1e30f, l_ = 0.f;

    // staging: thread t (0..511) covers row r8 = t>>3 (0..63), slot t&7;
    // writes LDS 16B chunk at slot (t&7)^(r8&7). Read side applies same XOR.
    const int r8 = t >> 3;
    const int lcol = (t & 7) * 16;
    const int swoff = (r8 * 128) + (lcol ^ ((r8 & 7) << 4));
    const char* kp0 = (const char*)Kh + (size_t)r8 * 128 + lcol;   // +8192/tile
    const char* vp0 = (const char*)Vh + (size_t)r8 * 4096 + lcol;  // +128/tile
    char* KsB = (char*)Ks;
    char* VsB = (char*)Vs;
    const int sw = (li & 7) << 4;

    i32x4 gk0 = *(const i32x4*)(kp0);
    i32x4 gv0 = *(const i32x4*)(vp0);
    // prologue: stage tile 0 into buf0, load tile 1 into regs
    *(i32x4*)(KsB + swoff) = gk0;
    *(i32x4*)(VsB + swoff) = gv0;
    gk0 = *(const i32x4*)(kp0 + 8192);
    gv0 = *(const i32x4*)(vp0 + 128);
    __syncthreads();

    for (int it = 0; it < 32; ++it) {
        const int cur = it & 1;
        // stage tile it+1 into buf cur^1 (free: all waves left it after barrier)
        if (it < 31) {
            const int nb = (cur ^ 1) * 8192;
            *(i32x4*)(KsB + nb + swoff) = gk0;
            *(i32x4*)(VsB + nb + swoff) = gv0;
        }
        if (it < 30) {  // issue tile it+2 loads; latency hides under compute
            gk0 = *(const i32x4*)(kp0 + (size_t)(it + 2) * 8192);
            gv0 = *(const i32x4*)(vp0 + (size_t)(it + 2) * 128);
        }

        const char* kb = KsB + cur * 8192;
        const char* vb = VsB + cur * 8192;

        // --- QK^T: S^T[kv][q], two 32-kv halves ---
        f32x16 s0 = z16, s1 = z16;
        __builtin_amdgcn_s_setprio(1);
#pragma unroll
        for (int ks = 0; ks < 4; ++ks) {
            const int b = ks * 32 + hi * 16;
            bf16x8 k0 = *(const bf16x8*)(kb + li * 128 + (b ^ sw));
            bf16x8 k1 = *(const bf16x8*)(kb + (32 + li) * 128 + (b ^ sw));
            s0 = __builtin_amdgcn_mfma_f32_32x32x16_bf16(k0, qf[ks], s0, 0, 0, 0);
            s1 = __builtin_amdgcn_mfma_f32_32x32x16_bf16(k1, qf[ks], s1, 0, 0, 0);
        }
        __builtin_amdgcn_s_setprio(0);

        // --- online softmax (log2 domain), lane-local rows, tree max ---
        float mx[8];
#pragma unroll
        for (int j = 0; j < 8; ++j)
            mx[j] = fmaxf(fmaxf(s0[j], s0[j + 8]), fmaxf(s1[j], s1[j + 8]));
        float m01 = fmaxf(mx[0], mx[1]), m23 = fmaxf(mx[2], mx[3]);
        float m45 = fmaxf(mx[4], mx[5]), m67 = fmaxf(mx[6], mx[7]);
        float tm = fmaxf(fmaxf(m01, m23), fmaxf(m45, m67));
        tm = fmaxf(tm, __shfl_xor(tm, 32));
        if (__any(tm > m_ + 8.f)) {  // defer-max (T13)
            float mn = fmaxf(m_, tm);
            float corr = vexp2(m_ - mn);
#pragma unroll
            for (int r = 0; r < 16; ++r) { o0[r] *= corr; o1[r] *= corr; }
            l_ *= corr;
            m_ = mn;
        }
#pragma unroll
        for (int r = 0; r < 16; ++r) s0[r] = vexp2(s0[r] - m_);
#pragma unroll
        for (int r = 0; r < 16; ++r) s1[r] = vexp2(s1[r] - m_);
        // --- row sum (r6-verified VALU tree) ---
        float su[8];
#pragma unroll
        for (int j = 0; j < 8; ++j)
            su[j] = (s0[j] + s0[j + 8]) + (s1[j] + s1[j + 8]);
        float s01 = su[0] + su[1], s23 = su[2] + su[3];
        float s45 = su[4] + su[5], s67 = su[6] + su[7];
        float sum = (s01 + s23) + (s45 + s67);
        sum += __shfl_xor(sum, 32);
        l_ += sum;

        // --- pack P -> 4 B-frags (verified path) ---
        bf16x8 pf[4];
        pf[0] = mkfrag(s0[0], s0[1], s0[2], s0[3], s0[4], s0[5], s0[6], s0[7], hi);
        pf[1] = mkfrag(s0[8], s0[9], s0[10], s0[11], s0[12], s0[13], s0[14], s0[15], hi);
        pf[2] = mkfrag(s1[0], s1[1], s1[2], s1[3], s1[4], s1[5], s1[6], s1[7], hi);
        pf[3] = mkfrag(s1[8], s1[9], s1[10], s1[11], s1[12], s1[13], s1[14], s1[15], hi);

        // --- PV: O^T[d][q] += V^T . P^T ---
        __builtin_amdgcn_s_setprio(1);
#pragma unroll
        for (int ks = 0; ks < 4; ++ks) {
            const int b = ks * 32 + hi * 16;
            bf16x8 v0 = *(const bf16x8*)(vb + li * 128 + (b ^ sw));
            bf16x8 v1 = *(const bf16x8*)(vb + (32 + li) * 128 + (b ^ sw));
            o0 = __builtin_amdgcn_mfma_f32_32x32x16_bf16(v0, pf[ks], o0, 0, 0, 0);
            o1 = __builtin_amdgcn_mfma_f32_32x32x16_bf16(v1, pf[ks], o1, 0, 0, 0);
        }
        __builtin_amdgcn_s_setprio(0);

        __syncthreads();  // writes to cur^1 visible; everyone done reading cur
    }

    // --- epilogue: lane (li,hi) owns q=qbase+li; o_dt[r] = O^T[d][q],
    //     d = (r&3) + 8*(r>>2) + 4*hi + 32*dt.  l = l_. ---
    const float rl = 1.0f / l_;
    const int b = pair >> 4, hh = pair & 15;
    const int s = qbase + li;
    const size_t rowbase = ((size_t)(b * 2048 + s)) * 1024 + hh * 64;
#pragma unroll
    for (int dt = 0; dt < 2; ++dt) {
#pragma unroll
        for (int rq = 0; rq < 4; ++rq) {
            float v0 = (dt ? o1[rq * 4 + 0] : o0[rq * 4 + 0]) * rl;
            float v1 = (dt ? o1[rq * 4 + 1] : o0[rq * 4 + 1]) * rl;
            float v2 = (dt ? o1[rq * 4 + 2] : o0[rq * 4 + 2]) * rl;
            float v3 = (dt ? o1[rq * 4 + 3] : o0[rq * 4 + 3]) * rl;
            u32x2 uv;
            uv[0] = pkbf(v0, v1);
            uv[1] = pkbf(v2, v3);
            *(u32x2*)&Oa[rowbase + dt * 32 + rq * 8 + hi * 4] = uv;
        }
    }
}

extern "C" void kernel_launch(void* const* d_in, const int* in_sizes, int n_in,
                              void* d_out, int out_size, void* d_ws, size_t ws_size,
                              hipStream_t stream) {
    const float* query = (const float*)d_in[0];
    const float* key_ = (const float*)d_in[1];
    const float* value = (const float*)d_in[2];
    const float* Wq = (const float*)d_in[3];
    const float* bq = (const float*)d_in[4];
    const float* Wk = (const float*)d_in[5];
    const float* bk = (const float*)d_in[6];
    const float* Wv = (const float*)d_in[7];
    const float* bv = (const float*)d_in[8];
    const float* Wo = (const float*)d_in[9];
    const float* bo = (const float*)d_in[10];
    float* out = (float*)d_out;

    char* ws = (char*)d_ws;
    ushort_t* Wqt = (ushort_t*)(ws + 0);
    ushort_t* Wkt = (ushort_t*)(ws + 2097152);
    ushort_t* Wvt = (ushort_t*)(ws + 4194304);
    ushort_t* Wot = (ushort_t*)(ws + 6291456);
    ushort_t* Qp = (ushort_t*)(ws + 8388608);
    ushort_t* Kp = (ushort_t*)(ws + 25165824);
    ushort_t* Vt = (ushort_t*)(ws + 58720256);
    ushort_t* Oa = (ushort_t*)(ws + 41943040);

    transpose_cast4<<<4096, 256, 0, stream>>>(Wq, Wk, Wv, Wo, Wqt, Wkt, Wvt, Wot);

    gemm_qkv<<<1536, 256, 0, stream>>>(query, key_, value, Wqt, Wkt, Wvt,
                                       bq, bk, bv, Qp, Kp, Vt);

    attn_kernel<<<512, 512, 0, stream>>>(Qp, Kp, Vt, Oa);

    gemm_out<<<512, 256, 0, stream>>>(Oa, Wot, bo, out);
}

// Round 19
// 217.216 us; speedup vs baseline: 1.3733x; 1.0095x over previous
//
#include <hip/hip_runtime.h>

typedef unsigned short ushort_t;
typedef __attribute__((ext_vector_type(8))) short bf16x8;
typedef __attribute__((ext_vector_type(4))) float f32x4;
typedef __attribute__((ext_vector_type(16))) float f32x16;
typedef __attribute__((ext_vector_type(4))) int i32x4;
typedef __attribute__((ext_vector_type(2))) unsigned int u32x2;

#define QSCALE 0.1803368801111204f  /* (1/8) * log2(e): softmax in log2 domain */

__device__ inline ushort_t f2bf(float f) {
    unsigned int u = __float_as_uint(f);
    unsigned int r = (u + 0x7FFFu + ((u >> 16) & 1u)) >> 16;
    return (ushort_t)r;
}
// packed bf16 convert (VERIFIED round 7): dst = {lo: bf16(x), hi: bf16(y)}
__device__ inline unsigned pkbf(float x, float y) {
    unsigned d;
    asm("v_cvt_pk_bf16_f32 %0, %1, %2" : "=v"(d) : "v"(x), "v"(y));
    return d;
}
// single-instruction 2^x (VERIFIED round 11)
__device__ inline float vexp2(float x) {
    float r;
    asm("v_exp_f32 %0, %1" : "=v"(r) : "v"(x));
    return r;
}
__device__ inline bf16x8 frag_from(unsigned a, unsigned b, unsigned c, unsigned d) {
    union { i32x4 i; bf16x8 v; } u;
    u.i[0] = (int)a; u.i[1] = (int)b; u.i[2] = (int)c; u.i[3] = (int)d;
    return u.v;
}

// P-fragment builder (movement VERIFIED r4; cvt_pk pack VERIFIED r7):
// lane (li,hi) holds P[q=li][kv_local=(r&3)+8*(r>>2)+4*hi] in x0..x7.
// Produces B-frag: B[k=hi*8+j][col=li].
__device__ inline bf16x8 mkfrag(float x0, float x1, float x2, float x3,
                                float x4, float x5, float x6, float x7, int hi) {
    unsigned A_ = pkbf(x0, x1), B_ = pkbf(x2, x3), C_ = pkbf(x4, x5), D_ = pkbf(x6, x7);
    unsigned Ax = (unsigned)__shfl_xor((int)A_, 32);
    unsigned Bx = (unsigned)__shfl_xor((int)B_, 32);
    unsigned Cx = (unsigned)__shfl_xor((int)C_, 32);
    unsigned Dx = (unsigned)__shfl_xor((int)D_, 32);
    return frag_from(hi ? Cx : A_, hi ? Dx : B_, hi ? C_ : Ax, hi ? D_ : Bx);
}

// ------------- transpose + cast all 4 weights: W[K,N] f32 -> Wt[N,K] bf16 ----
__global__ __launch_bounds__(256) void transpose_cast4(
    const float* __restrict__ W0, const float* __restrict__ W1,
    const float* __restrict__ W2, const float* __restrict__ W3,
    ushort_t* __restrict__ T0, ushort_t* __restrict__ T1,
    ushort_t* __restrict__ T2, ushort_t* __restrict__ T3) {
    __shared__ float tile[32][33];
    const int which = blockIdx.x >> 10;
    const float* W = which == 0 ? W0 : which == 1 ? W1 : which == 2 ? W2 : W3;
    ushort_t* Wt = which == 0 ? T0 : which == 1 ? T1 : which == 2 ? T2 : T3;
    const int bidx = blockIdx.x & 1023;
    const int bx = bidx & 31, by = bidx >> 5;
    const int n0 = bx * 32, k0 = by * 32;
    const int tx = threadIdx.x & 31, ty = threadIdx.x >> 5;
#pragma unroll
    for (int i = 0; i < 4; ++i) {
        int r = ty + i * 8;
        tile[r][tx] = W[(k0 + r) * 1024 + n0 + tx];
    }
    __syncthreads();
#pragma unroll
    for (int i = 0; i < 4; ++i) {
        int r = ty + i * 8;
        Wt[(n0 + r) * 1024 + k0 + tx] = f2bf(tile[tx][r]);
    }
}

// ------------- merged QKV projection GEMM (r16-verified body) ----------------
// 1536 blocks: which = bid>>9 selects {query->Qp(OMODE0,QSCALE), key->Kp(OMODE0),
// value->Vt(OMODE2 transposed split-heads)}. 128x128 tile, 256 thr, padded-72.
// XCD-chunked + bn-minor remap: XCD x owns bm in [8x,8x+8) x all bn -> each
// 512KB A-panel fetched once into its L2, reused 8x (T1).
__global__ __launch_bounds__(256) void gemm_qkv(
    const float* __restrict__ Aq, const float* __restrict__ Ak,
    const float* __restrict__ Av,
    const ushort_t* __restrict__ Wq, const ushort_t* __restrict__ Wk,
    const ushort_t* __restrict__ Wv,
    const float* __restrict__ bq, const float* __restrict__ bk,
    const float* __restrict__ bv,
    ushort_t* __restrict__ Qp, ushort_t* __restrict__ Kp,
    ushort_t* __restrict__ Vt) {
    __shared__ alignas(16) ushort_t As[128 * 72];
    __shared__ alignas(16) ushort_t Bs[128 * 72];
    const int which = blockIdx.x >> 9;
    const int bid = blockIdx.x & 511;
    // bijective: r = (bid%8)*64 + bid/8; bm = r>>3 (0..63), bn = r&7 (0..7)
    const int r_ = (bid & 7) * 64 + (bid >> 3);
    const int bm = r_ >> 3, bn = r_ & 7;
    const float* A = which == 0 ? Aq : which == 1 ? Ak : Av;
    const ushort_t* Bt = which == 0 ? Wq : which == 1 ? Wk : Wv;
    const float* bias = which == 0 ? bq : which == 1 ? bk : bv;
    const float scale = which == 0 ? QSCALE : 1.0f;

    const int t = threadIdx.x;
    const int lane = t & 63, w = t >> 6;
    const int q = lane & 15, g = lane >> 4;
    const int wr = w >> 1, wc = w & 1;
    const int m0 = bm * 128, n0 = bn * 128;

    f32x4 acc[4][4];
#pragma unroll
    for (int i = 0; i < 4; ++i)
#pragma unroll
        for (int j = 0; j < 4; ++j) acc[i][j] = (f32x4){0.f, 0.f, 0.f, 0.f};

    for (int k0 = 0; k0 < 1024; k0 += 64) {
        __syncthreads();
#pragma unroll
        for (int it = 0; it < 4; ++it) {
            int tt = t + it * 256;
            int row = tt >> 3;
            int col = (tt & 7) * 8;
            float4 v0 = *(const float4*)&A[(size_t)(m0 + row) * 1024 + k0 + col];
            float4 v1 = *(const float4*)&A[(size_t)(m0 + row) * 1024 + k0 + col + 4];
            *(bf16x8*)&As[row * 72 + col] =
                frag_from(pkbf(v0.x, v0.y), pkbf(v0.z, v0.w),
                          pkbf(v1.x, v1.y), pkbf(v1.z, v1.w));
            *(bf16x8*)&Bs[row * 72 + col] =
                *(const bf16x8*)&Bt[(size_t)(n0 + row) * 1024 + k0 + col];
        }
        __syncthreads();
#pragma unroll
        for (int kt = 0; kt < 2; ++kt) {
            bf16x8 af[4], bfr[4];
#pragma unroll
            for (int mt = 0; mt < 4; ++mt)
                af[mt] = *(const bf16x8*)&As[(wr * 64 + mt * 16 + q) * 72 + kt * 32 + g * 8];
#pragma unroll
            for (int nt = 0; nt < 4; ++nt)
                bfr[nt] = *(const bf16x8*)&Bs[(wc * 64 + nt * 16 + q) * 72 + kt * 32 + g * 8];
#pragma unroll
            for (int mt = 0; mt < 4; ++mt)
#pragma unroll
                for (int nt = 0; nt < 4; ++nt)
                    acc[mt][nt] = __builtin_amdgcn_mfma_f32_16x16x32_bf16(
                        af[mt], bfr[nt], acc[mt][nt], 0, 0, 0);
        }
    }

#pragma unroll
    for (int mt = 0; mt < 4; ++mt) {
#pragma unroll
        for (int nt = 0; nt < 4; ++nt) {
            const int col = n0 + wc * 64 + nt * 16 + q;
            if (which == 2) {  // OMODE 2: Vt[B,H,D,S], 4 consecutive s -> 8B store
                const int grow0 = m0 + wr * 64 + mt * 16 + g * 4;
                const int b = grow0 >> 11, si = grow0 & 2047;
                const int h = col >> 6, d = col & 63;
                float v0 = acc[mt][nt][0] + bias[col];
                float v1 = acc[mt][nt][1] + bias[col];
                float v2 = acc[mt][nt][2] + bias[col];
                float v3 = acc[mt][nt][3] + bias[col];
                u32x2 uv;
                uv[0] = pkbf(v0, v1);
                uv[1] = pkbf(v2, v3);
                *(u32x2*)&Vt[((size_t)((b * 16 + h) * 64 + d)) * 2048 + si] = uv;
            } else {  // OMODE 0: [B,H,S,D] bf16, scaled
                ushort_t* outp = which == 0 ? Qp : Kp;
#pragma unroll
                for (int r = 0; r < 4; ++r) {
                    int grow = m0 + wr * 64 + mt * 16 + g * 4 + r;
                    float v = acc[mt][nt][r] + bias[col];
                    int b = grow >> 11, s = grow & 2047;
                    int h = col >> 6, d = col & 63;
                    outp[(((size_t)(b * 16 + h) * 2048 + s) * 64) + d] = f2bf(v * scale);
                }
            }
        }
    }
}

// ---------------- final GEMM: out[M,1024] f32 = Oa[M,1024]bf16 @ Wot^T + bo --
// Same XCD-chunked + bn-minor remap (512 blocks).
__global__ __launch_bounds__(256) void gemm_out(const ushort_t* __restrict__ Ap,
                                                const ushort_t* __restrict__ Bt,
                                                const float* __restrict__ bias,
                                                float* __restrict__ out) {
    __shared__ alignas(16) ushort_t As[128 * 72];
    __shared__ alignas(16) ushort_t Bs[128 * 72];
    const int t = threadIdx.x;
    const int lane = t & 63, w = t >> 6;
    const int q = lane & 15, g = lane >> 4;
    const int wr = w >> 1, wc = w & 1;
    const int r_ = ((blockIdx.x & 7) * 64) + (blockIdx.x >> 3);
    const int bm = r_ >> 3, bn = r_ & 7;
    const int m0 = bm * 128, n0 = bn * 128;

    f32x4 acc[4][4];
#pragma unroll
    for (int i = 0; i < 4; ++i)
#pragma unroll
        for (int j = 0; j < 4; ++j) acc[i][j] = (f32x4){0.f, 0.f, 0.f, 0.f};

    for (int k0 = 0; k0 < 1024; k0 += 64) {
        __syncthreads();
#pragma unroll
        for (int it = 0; it < 4; ++it) {
            int tt = t + it * 256;
            int row = tt >> 3;
            int col = (tt & 7) * 8;
            *(bf16x8*)&As[row * 72 + col] =
                *(const bf16x8*)&Ap[(size_t)(m0 + row) * 1024 + k0 + col];
            *(bf16x8*)&Bs[row * 72 + col] =
                *(const bf16x8*)&Bt[(size_t)(n0 + row) * 1024 + k0 + col];
        }
        __syncthreads();
#pragma unroll
        for (int kt = 0; kt < 2; ++kt) {
            bf16x8 af[4], bfr[4];
#pragma unroll
            for (int mt = 0; mt < 4; ++mt)
                af[mt] = *(const bf16x8*)&As[(wr * 64 + mt * 16 + q) * 72 + kt * 32 + g * 8];
#pragma unroll
            for (int nt = 0; nt < 4; ++nt)
                bfr[nt] = *(const bf16x8*)&Bs[(wc * 64 + nt * 16 + q) * 72 + kt * 32 + g * 8];
#pragma unroll
            for (int mt = 0; mt < 4; ++mt)
#pragma unroll
                for (int nt = 0; nt < 4; ++nt)
                    acc[mt][nt] = __builtin_amdgcn_mfma_f32_16x16x32_bf16(
                        af[mt], bfr[nt], acc[mt][nt], 0, 0, 0);
        }
    }

#pragma unroll
    for (int mt = 0; mt < 4; ++mt) {
#pragma unroll
        for (int nt = 0; nt < 4; ++nt) {
            const int col = n0 + wc * 64 + nt * 16 + q;
#pragma unroll
            for (int r = 0; r < 4; ++r) {
                int grow = m0 + wr * 64 + mt * 16 + g * 4 + r;
                out[(size_t)grow * 1024 + col] = acc[mt][nt][r] + bias[col];
            }
        }
    }
}

// ---------------- flash attention, 32x32 swapped-operand, reg-staged K/V -----
// r12/r16-VERIFIED best (103.7-104.3 us): 8 waves x 32 q = 256 q/block;
// grid 512; reg-staged double-buffered K/V, vexp2, VALU sum tree.
__global__ __launch_bounds__(512, 4) void attn_kernel(const ushort_t* __restrict__ Qp,
                                                      const ushort_t* __restrict__ Kp,
                                                      const ushort_t* __restrict__ Vtp,
                                                      ushort_t* __restrict__ Oa) {
    __shared__ alignas(16) ushort_t Ks[2][4096];  // [64 kv][64 d], rows XOR-swizzled
    __shared__ alignas(16) ushort_t Vs[2][4096];  // [64 d][64 kv], rows XOR-swizzled

    const int t = threadIdx.x, lane = t & 63, w = t >> 6;  // w 0..7
    const int li = lane & 31, hi = lane >> 5;
    // XCD-contiguous remap: 512 = 8 xcd * 64 (bijective); pair = bid>>3
    const int bid = (blockIdx.x & 7) * 64 + (blockIdx.x >> 3);
    const int pair = bid >> 3;
    const int qbase = (bid & 7) * 256 + w * 32;

    const ushort_t* Qh = Qp + (size_t)pair * 2048 * 64;
    const ushort_t* Kh = Kp + (size_t)pair * 2048 * 64;
    const ushort_t* Vh = Vtp + (size_t)pair * 64 * 2048;

    // Q B-frags: B[k][col=li] = Q[qbase+li][k], k = ks*16 + hi*8 + j
    bf16x8 qf[4];
#pragma unroll
    for (int ks = 0; ks < 4; ++ks)
        qf[ks] = *(const bf16x8*)&Qh[(size_t)(qbase + li) * 64 + ks * 16 + hi * 8];

    const f32x16 z16 = {0.f,0.f,0.f,0.f,0.f,0.f,0.f,0.f,0.f,0.f,0.f,0.f,0.f,0.f,0.f,0.f};
    f32x16 o0 = z16, o1 = z16;
    float m_ = -1e30f, l_ = 0.f;

    // staging: thread t (0..511) covers row r8 = t>>3 (0..63), slot t&7;
    // writes LDS 16B chunk at slot (t&7)^(r8&7). Read side applies same XOR.
    const int r8 = t >> 3;
    const int lcol = (t & 7) * 16;
    const int swoff = (r8 * 128) + (lcol ^ ((r8 & 7) << 4));
    const char* kp0 = (const char*)Kh + (size_t)r8 * 128 + lcol;   // +8192/tile
    const char* vp0 = (const char*)Vh + (size_t)r8 * 4096 + lcol;  // +128/tile
    char* KsB = (char*)Ks;
    char* VsB = (char*)Vs;
    const int sw = (li & 7) << 4;

    i32x4 gk0 = *(const i32x4*)(kp0);
    i32x4 gv0 = *(const i32x4*)(vp0);
    // prologue: stage tile 0 into buf0, load tile 1 into regs
    *(i32x4*)(KsB + swoff) = gk0;
    *(i32x4*)(VsB + swoff) = gv0;
    gk0 = *(const i32x4*)(kp0 + 8192);
    gv0 = *(const i32x4*)(vp0 + 128);
    __syncthreads();

    for (int it = 0; it < 32; ++it) {
        const int cur = it & 1;
        // stage tile it+1 into buf cur^1 (free: all waves left it after barrier)
        if (it < 31) {
            const int nb = (cur ^ 1) * 8192;
            *(i32x4*)(KsB + nb + swoff) = gk0;
            *(i32x4*)(VsB + nb + swoff) = gv0;
        }
        if (it < 30) {  // issue tile it+2 loads; latency hides under compute
            gk0 = *(const i32x4*)(kp0 + (size_t)(it + 2) * 8192);
            gv0 = *(const i32x4*)(vp0 + (size_t)(it + 2) * 128);
        }

        const char* kb = KsB + cur * 8192;
        const char* vb = VsB + cur * 8192;

        // --- QK^T: S^T[kv][q], two 32-kv halves ---
        f32x16 s0 = z16, s1 = z16;
        __builtin_amdgcn_s_setprio(1);
#pragma unroll
        for (int ks = 0; ks < 4; ++ks) {
            const int b = ks * 32 + hi * 16;
            bf16x8 k0 = *(const bf16x8*)(kb + li * 128 + (b ^ sw));
            bf16x8 k1 = *(const bf16x8*)(kb + (32 + li) * 128 + (b ^ sw));
            s0 = __builtin_amdgcn_mfma_f32_32x32x16_bf16(k0, qf[ks], s0, 0, 0, 0);
            s1 = __builtin_amdgcn_mfma_f32_32x32x16_bf16(k1, qf[ks], s1, 0, 0, 0);
        }
        __builtin_amdgcn_s_setprio(0);

        // --- online softmax (log2 domain), lane-local rows, tree max ---
        float mx[8];
#pragma unroll
        for (int j = 0; j < 8; ++j)
            mx[j] = fmaxf(fmaxf(s0[j], s0[j + 8]), fmaxf(s1[j], s1[j + 8]));
        float m01 = fmaxf(mx[0], mx[1]), m23 = fmaxf(mx[2], mx[3]);
        float m45 = fmaxf(mx[4], mx[5]), m67 = fmaxf(mx[6], mx[7]);
        float tm = fmaxf(fmaxf(m01, m23), fmaxf(m45, m67));
        tm = fmaxf(tm, __shfl_xor(tm, 32));
        if (__any(tm > m_ + 8.f)) {  // defer-max (T13)
            float mn = fmaxf(m_, tm);
            float corr = vexp2(m_ - mn);
#pragma unroll
            for (int r = 0; r < 16; ++r) { o0[r] *= corr; o1[r] *= corr; }
            l_ *= corr;
            m_ = mn;
        }
#pragma unroll
        for (int r = 0; r < 16; ++r) s0[r] = vexp2(s0[r] - m_);
#pragma unroll
        for (int r = 0; r < 16; ++r) s1[r] = vexp2(s1[r] - m_);
        // --- row sum (r6-verified VALU tree) ---
        float su[8];
#pragma unroll
        for (int j = 0; j < 8; ++j)
            su[j] = (s0[j] + s0[j + 8]) + (s1[j] + s1[j + 8]);
        float s01 = su[0] + su[1], s23 = su[2] + su[3];
        float s45 = su[4] + su[5], s67 = su[6] + su[7];
        float sum = (s01 + s23) + (s45 + s67);
        sum += __shfl_xor(sum, 32);
        l_ += sum;

        // --- pack P -> 4 B-frags (verified path) ---
        bf16x8 pf[4];
        pf[0] = mkfrag(s0[0], s0[1], s0[2], s0[3], s0[4], s0[5], s0[6], s0[7], hi);
        pf[1] = mkfrag(s0[8], s0[9], s0[10], s0[11], s0[12], s0[13], s0[14], s0[15], hi);
        pf[2] = mkfrag(s1[0], s1[1], s1[2], s1[3], s1[4], s1[5], s1[6], s1[7], hi);
        pf[3] = mkfrag(s1[8], s1[9], s1[10], s1[11], s1[12], s1[13], s1[14], s1[15], hi);

        // --- PV: O^T[d][q] += V^T . P^T ---
        __builtin_amdgcn_s_setprio(1);
#pragma unroll
        for (int ks = 0; ks < 4; ++ks) {
            const int b = ks * 32 + hi * 16;
            bf16x8 v0 = *(const bf16x8*)(vb + li * 128 + (b ^ sw));
            bf16x8 v1 = *(const bf16x8*)(vb + (32 + li) * 128 + (b ^ sw));
            o0 = __builtin_amdgcn_mfma_f32_32x32x16_bf16(v0, pf[ks], o0, 0, 0, 0);
            o1 = __builtin_amdgcn_mfma_f32_32x32x16_bf16(v1, pf[ks], o1, 0, 0, 0);
        }
        __builtin_amdgcn_s_setprio(0);

        __syncthreads();  // writes to cur^1 visible; everyone done reading cur
    }

    // --- epilogue: lane (li,hi) owns q=qbase+li; o_dt[r] = O^T[d][q],
    //     d = (r&3) + 8*(r>>2) + 4*hi + 32*dt.  l = l_. ---
    const float rl = 1.0f / l_;
    const int b = pair >> 4, hh = pair & 15;
    const int s = qbase + li;
    const size_t rowbase = ((size_t)(b * 2048 + s)) * 1024 + hh * 64;
#pragma unroll
    for (int dt = 0; dt < 2; ++dt) {
#pragma unroll
        for (int rq = 0; rq < 4; ++rq) {
            float v0 = (dt ? o1[rq * 4 + 0] : o0[rq * 4 + 0]) * rl;
            float v1 = (dt ? o1[rq * 4 + 1] : o0[rq * 4 + 1]) * rl;
            float v2 = (dt ? o1[rq * 4 + 2] : o0[rq * 4 + 2]) * rl;
            float v3 = (dt ? o1[rq * 4 + 3] : o0[rq * 4 + 3]) * rl;
            u32x2 uv;
            uv[0] = pkbf(v0, v1);
            uv[1] = pkbf(v2, v3);
            *(u32x2*)&Oa[rowbase + dt * 32 + rq * 8 + hi * 4] = uv;
        }
    }
}

extern "C" void kernel_launch(void* const* d_in, const int* in_sizes, int n_in,
                              void* d_out, int out_size, void* d_ws, size_t ws_size,
                              hipStream_t stream) {
    const float* query = (const float*)d_in[0];
    const float* key_ = (const float*)d_in[1];
    const float* value = (const float*)d_in[2];
    const float* Wq = (const float*)d_in[3];
    const float* bq = (const float*)d_in[4];
    const float* Wk = (const float*)d_in[5];
    const float* bk = (const float*)d_in[6];
    const float* Wv = (const float*)d_in[7];
    const float* bv = (const float*)d_in[8];
    const float* Wo = (const float*)d_in[9];
    const float* bo = (const float*)d_in[10];
    float* out = (float*)d_out;

    char* ws = (char*)d_ws;
    ushort_t* Wqt = (ushort_t*)(ws + 0);
    ushort_t* Wkt = (ushort_t*)(ws + 2097152);
    ushort_t* Wvt = (ushort_t*)(ws + 4194304);
    ushort_t* Wot = (ushort_t*)(ws + 6291456);
    ushort_t* Qp = (ushort_t*)(ws + 8388608);
    ushort_t* Kp = (ushort_t*)(ws + 25165824);
    ushort_t* Vt = (ushort_t*)(ws + 58720256);
    ushort_t* Oa = (ushort_t*)(ws + 41943040);

    transpose_cast4<<<4096, 256, 0, stream>>>(Wq, Wk, Wv, Wo, Wqt, Wkt, Wvt, Wot);

    gemm_qkv<<<1536, 256, 0, stream>>>(query, key_, value, Wqt, Wkt, Wvt,
                                       bq, bk, bv, Qp, Kp, Vt);

    attn_kernel<<<512, 512, 0, stream>>>(Qp, Kp, Vt, Oa);

    gemm_out<<<512, 256, 0, stream>>>(Oa, Wot, bo, out);
}

// Round 20
// 212.226 us; speedup vs baseline: 1.4056x; 1.0235x over previous
//
#include <hip/hip_runtime.h>

typedef unsigned short ushort_t;
typedef __attribute__((ext_vector_type(8))) short bf16x8;
typedef __attribute__((ext_vector_type(4))) float f32x4;
typedef __attribute__((ext_vector_type(16))) float f32x16;
typedef __attribute__((ext_vector_type(4))) int i32x4;
typedef __attribute__((ext_vector_type(2))) unsigned int u32x2;

#define QSCALE 0.1803368801111204f  /* (1/8) * log2(e): softmax in log2 domain */

__device__ inline ushort_t f2bf(float f) {
    unsigned int u = __float_as_uint(f);
    unsigned int r = (u + 0x7FFFu + ((u >> 16) & 1u)) >> 16;
    return (ushort_t)r;
}
// packed bf16 convert (VERIFIED round 7): dst = {lo: bf16(x), hi: bf16(y)}
__device__ inline unsigned pkbf(float x, float y) {
    unsigned d;
    asm("v_cvt_pk_bf16_f32 %0, %1, %2" : "=v"(d) : "v"(x), "v"(y));
    return d;
}
// single-instruction 2^x (VERIFIED round 11)
__device__ inline float vexp2(float x) {
    float r;
    asm("v_exp_f32 %0, %1" : "=v"(r) : "v"(x));
    return r;
}
__device__ inline bf16x8 frag_from(unsigned a, unsigned b, unsigned c, unsigned d) {
    union { i32x4 i; bf16x8 v; } u;
    u.i[0] = (int)a; u.i[1] = (int)b; u.i[2] = (int)c; u.i[3] = (int)d;
    return u.v;
}

// P-fragment builder (movement VERIFIED r4; cvt_pk pack VERIFIED r7):
// lane (li,hi) holds P[q=li][kv_local=(r&3)+8*(r>>2)+4*hi] in x0..x7.
// Produces B-frag: B[k=hi*8+j][col=li].
__device__ inline bf16x8 mkfrag(float x0, float x1, float x2, float x3,
                                float x4, float x5, float x6, float x7, int hi) {
    unsigned A_ = pkbf(x0, x1), B_ = pkbf(x2, x3), C_ = pkbf(x4, x5), D_ = pkbf(x6, x7);
    unsigned Ax = (unsigned)__shfl_xor((int)A_, 32);
    unsigned Bx = (unsigned)__shfl_xor((int)B_, 32);
    unsigned Cx = (unsigned)__shfl_xor((int)C_, 32);
    unsigned Dx = (unsigned)__shfl_xor((int)D_, 32);
    return frag_from(hi ? Cx : A_, hi ? Dx : B_, hi ? C_ : Ax, hi ? D_ : Bx);
}

// ------------- transpose + cast all 4 weights: W[K,N] f32 -> Wt[N,K] bf16 ----
__global__ __launch_bounds__(256) void transpose_cast4(
    const float* __restrict__ W0, const float* __restrict__ W1,
    const float* __restrict__ W2, const float* __restrict__ W3,
    ushort_t* __restrict__ T0, ushort_t* __restrict__ T1,
    ushort_t* __restrict__ T2, ushort_t* __restrict__ T3) {
    __shared__ float tile[32][33];
    const int which = blockIdx.x >> 10;
    const float* W = which == 0 ? W0 : which == 1 ? W1 : which == 2 ? W2 : W3;
    ushort_t* Wt = which == 0 ? T0 : which == 1 ? T1 : which == 2 ? T2 : T3;
    const int bidx = blockIdx.x & 1023;
    const int bx = bidx & 31, by = bidx >> 5;
    const int n0 = bx * 32, k0 = by * 32;
    const int tx = threadIdx.x & 31, ty = threadIdx.x >> 5;
#pragma unroll
    for (int i = 0; i < 4; ++i) {
        int r = ty + i * 8;
        tile[r][tx] = W[(k0 + r) * 1024 + n0 + tx];
    }
    __syncthreads();
#pragma unroll
    for (int i = 0; i < 4; ++i) {
        int r = ty + i * 8;
        Wt[(n0 + r) * 1024 + k0 + tx] = f2bf(tile[tx][r]);
    }
}

// ------------- merged QKV projection GEMM, reg-prefetch pipeline -------------
// 1536 blocks: which = bid>>9 selects {query->Qp(OMODE0,QSCALE), key->Kp(OMODE0),
// value->Vt(OMODE2 transposed split-heads)}. 128x128 tile, 256 thr, padded-72.
// r4-verified prefetch pattern: loads for k+64 issue right after LDS writes of
// k; latency hides under the MFMA phase (was fully exposed -> latency-bound).
__global__ __launch_bounds__(256) void gemm_qkv(
    const float* __restrict__ Aq, const float* __restrict__ Ak,
    const float* __restrict__ Av,
    const ushort_t* __restrict__ Wq, const ushort_t* __restrict__ Wk,
    const ushort_t* __restrict__ Wv,
    const float* __restrict__ bq, const float* __restrict__ bk,
    const float* __restrict__ bv,
    ushort_t* __restrict__ Qp, ushort_t* __restrict__ Kp,
    ushort_t* __restrict__ Vt) {
    __shared__ alignas(16) ushort_t As[128 * 72];
    __shared__ alignas(16) ushort_t Bs[128 * 72];
    const int which = blockIdx.x >> 9;
    const int bid = blockIdx.x & 511;
    const int r_ = (bid & 7) * 64 + (bid >> 3);   // XCD-chunked, bn-minor
    const int bm = r_ >> 3, bn = r_ & 7;
    const float* A = which == 0 ? Aq : which == 1 ? Ak : Av;
    const ushort_t* Bt = which == 0 ? Wq : which == 1 ? Wk : Wv;
    const float* bias = which == 0 ? bq : which == 1 ? bk : bv;
    const float scale = which == 0 ? QSCALE : 1.0f;

    const int t = threadIdx.x;
    const int lane = t & 63, w = t >> 6;
    const int q = lane & 15, g = lane >> 4;
    const int wr = w >> 1, wc = w & 1;
    const int m0 = bm * 128, n0 = bn * 128;

    // per-thread staging coords (fixed across k)
    const int srow = t >> 3;                 // 0..31 (row within first 32-chunk)
    const int scol = (t & 7) * 8;            // element col within 64
    // rows covered: srow, srow+32, srow+64, srow+96 (it = 0..3)

    f32x4 acc[4][4];
#pragma unroll
    for (int i = 0; i < 4; ++i)
#pragma unroll
        for (int j = 0; j < 4; ++j) acc[i][j] = (f32x4){0.f, 0.f, 0.f, 0.f};

    float4 ra0[4], ra1[4];
    bf16x8 rb[4];
    // prologue: load k=0 tile into regs
#pragma unroll
    for (int it = 0; it < 4; ++it) {
        const int row = srow + it * 32;
        ra0[it] = *(const float4*)&A[(size_t)(m0 + row) * 1024 + scol];
        ra1[it] = *(const float4*)&A[(size_t)(m0 + row) * 1024 + scol + 4];
        rb[it] = *(const bf16x8*)&Bt[(size_t)(n0 + row) * 1024 + scol];
    }

    for (int k0 = 0; k0 < 1024; k0 += 64) {
        __syncthreads();  // previous compute done reading LDS
#pragma unroll
        for (int it = 0; it < 4; ++it) {
            const int row = srow + it * 32;
            *(bf16x8*)&As[row * 72 + scol] =
                frag_from(pkbf(ra0[it].x, ra0[it].y), pkbf(ra0[it].z, ra0[it].w),
                          pkbf(ra1[it].x, ra1[it].y), pkbf(ra1[it].z, ra1[it].w));
            *(bf16x8*)&Bs[row * 72 + scol] = rb[it];
        }
        if (k0 + 64 < 1024) {  // issue next-tile loads; hide under compute
            const int kn = k0 + 64;
#pragma unroll
            for (int it = 0; it < 4; ++it) {
                const int row = srow + it * 32;
                ra0[it] = *(const float4*)&A[(size_t)(m0 + row) * 1024 + kn + scol];
                ra1[it] = *(const float4*)&A[(size_t)(m0 + row) * 1024 + kn + scol + 4];
                rb[it] = *(const bf16x8*)&Bt[(size_t)(n0 + row) * 1024 + kn + scol];
            }
        }
        __syncthreads();  // tile staged
#pragma unroll
        for (int kt = 0; kt < 2; ++kt) {
            bf16x8 af[4], bfr[4];
#pragma unroll
            for (int mt = 0; mt < 4; ++mt)
                af[mt] = *(const bf16x8*)&As[(wr * 64 + mt * 16 + q) * 72 + kt * 32 + g * 8];
#pragma unroll
            for (int nt = 0; nt < 4; ++nt)
                bfr[nt] = *(const bf16x8*)&Bs[(wc * 64 + nt * 16 + q) * 72 + kt * 32 + g * 8];
#pragma unroll
            for (int mt = 0; mt < 4; ++mt)
#pragma unroll
                for (int nt = 0; nt < 4; ++nt)
                    acc[mt][nt] = __builtin_amdgcn_mfma_f32_16x16x32_bf16(
                        af[mt], bfr[nt], acc[mt][nt], 0, 0, 0);
        }
    }

#pragma unroll
    for (int mt = 0; mt < 4; ++mt) {
#pragma unroll
        for (int nt = 0; nt < 4; ++nt) {
            const int col = n0 + wc * 64 + nt * 16 + q;
            if (which == 2) {  // OMODE 2: Vt[B,H,D,S], 4 consecutive s -> 8B store
                const int grow0 = m0 + wr * 64 + mt * 16 + g * 4;
                const int b = grow0 >> 11, si = grow0 & 2047;
                const int h = col >> 6, d = col & 63;
                float v0 = acc[mt][nt][0] + bias[col];
                float v1 = acc[mt][nt][1] + bias[col];
                float v2 = acc[mt][nt][2] + bias[col];
                float v3 = acc[mt][nt][3] + bias[col];
                u32x2 uv;
                uv[0] = pkbf(v0, v1);
                uv[1] = pkbf(v2, v3);
                *(u32x2*)&Vt[((size_t)((b * 16 + h) * 64 + d)) * 2048 + si] = uv;
            } else {  // OMODE 0: [B,H,S,D] bf16, scaled
                ushort_t* outp = which == 0 ? Qp : Kp;
#pragma unroll
                for (int r = 0; r < 4; ++r) {
                    int grow = m0 + wr * 64 + mt * 16 + g * 4 + r;
                    float v = acc[mt][nt][r] + bias[col];
                    int b = grow >> 11, s = grow & 2047;
                    int h = col >> 6, d = col & 63;
                    outp[(((size_t)(b * 16 + h) * 2048 + s) * 64) + d] = f2bf(v * scale);
                }
            }
        }
    }
}

// ---------------- final GEMM: out[M,1024] f32 = Oa[M,1024]bf16 @ Wot^T + bo --
// Same reg-prefetch pipeline (bf16 A).
__global__ __launch_bounds__(256) void gemm_out(const ushort_t* __restrict__ Ap,
                                                const ushort_t* __restrict__ Bt,
                                                const float* __restrict__ bias,
                                                float* __restrict__ out) {
    __shared__ alignas(16) ushort_t As[128 * 72];
    __shared__ alignas(16) ushort_t Bs[128 * 72];
    const int t = threadIdx.x;
    const int lane = t & 63, w = t >> 6;
    const int q = lane & 15, g = lane >> 4;
    const int wr = w >> 1, wc = w & 1;
    const int r_ = ((blockIdx.x & 7) * 64) + (blockIdx.x >> 3);
    const int bm = r_ >> 3, bn = r_ & 7;
    const int m0 = bm * 128, n0 = bn * 128;

    const int srow = t >> 3;
    const int scol = (t & 7) * 8;

    f32x4 acc[4][4];
#pragma unroll
    for (int i = 0; i < 4; ++i)
#pragma unroll
        for (int j = 0; j < 4; ++j) acc[i][j] = (f32x4){0.f, 0.f, 0.f, 0.f};

    bf16x8 raf[4], rb[4];
#pragma unroll
    for (int it = 0; it < 4; ++it) {
        const int row = srow + it * 32;
        raf[it] = *(const bf16x8*)&Ap[(size_t)(m0 + row) * 1024 + scol];
        rb[it] = *(const bf16x8*)&Bt[(size_t)(n0 + row) * 1024 + scol];
    }

    for (int k0 = 0; k0 < 1024; k0 += 64) {
        __syncthreads();
#pragma unroll
        for (int it = 0; it < 4; ++it) {
            const int row = srow + it * 32;
            *(bf16x8*)&As[row * 72 + scol] = raf[it];
            *(bf16x8*)&Bs[row * 72 + scol] = rb[it];
        }
        if (k0 + 64 < 1024) {
            const int kn = k0 + 64;
#pragma unroll
            for (int it = 0; it < 4; ++it) {
                const int row = srow + it * 32;
                raf[it] = *(const bf16x8*)&Ap[(size_t)(m0 + row) * 1024 + kn + scol];
                rb[it] = *(const bf16x8*)&Bt[(size_t)(n0 + row) * 1024 + kn + scol];
            }
        }
        __syncthreads();
#pragma unroll
        for (int kt = 0; kt < 2; ++kt) {
            bf16x8 af[4], bfr[4];
#pragma unroll
            for (int mt = 0; mt < 4; ++mt)
                af[mt] = *(const bf16x8*)&As[(wr * 64 + mt * 16 + q) * 72 + kt * 32 + g * 8];
#pragma unroll
            for (int nt = 0; nt < 4; ++nt)
                bfr[nt] = *(const bf16x8*)&Bs[(wc * 64 + nt * 16 + q) * 72 + kt * 32 + g * 8];
#pragma unroll
            for (int mt = 0; mt < 4; ++mt)
#pragma unroll
                for (int nt = 0; nt < 4; ++nt)
                    acc[mt][nt] = __builtin_amdgcn_mfma_f32_16x16x32_bf16(
                        af[mt], bfr[nt], acc[mt][nt], 0, 0, 0);
        }
    }

#pragma unroll
    for (int mt = 0; mt < 4; ++mt) {
#pragma unroll
        for (int nt = 0; nt < 4; ++nt) {
            const int col = n0 + wc * 64 + nt * 16 + q;
#pragma unroll
            for (int r = 0; r < 4; ++r) {
                int grow = m0 + wr * 64 + mt * 16 + g * 4 + r;
                out[(size_t)grow * 1024 + col] = acc[mt][nt][r] + bias[col];
            }
        }
    }
}

// ---------------- flash attention, 32x32 swapped-operand, reg-staged K/V -----
// r12/r16-VERIFIED best (103.7-104.3 us): 8 waves x 32 q = 256 q/block;
// grid 512; reg-staged double-buffered K/V, vexp2, VALU sum tree.
__global__ __launch_bounds__(512, 4) void attn_kernel(const ushort_t* __restrict__ Qp,
                                                      const ushort_t* __restrict__ Kp,
                                                      const ushort_t* __restrict__ Vtp,
                                                      ushort_t* __restrict__ Oa) {
    __shared__ alignas(16) ushort_t Ks[2][4096];  // [64 kv][64 d], rows XOR-swizzled
    __shared__ alignas(16) ushort_t Vs[2][4096];  // [64 d][64 kv], rows XOR-swizzled

    const int t = threadIdx.x, lane = t & 63, w = t >> 6;  // w 0..7
    const int li = lane & 31, hi = lane >> 5;
    // XCD-contiguous remap: 512 = 8 xcd * 64 (bijective); pair = bid>>3
    const int bid = (blockIdx.x & 7) * 64 + (blockIdx.x >> 3);
    const int pair = bid >> 3;
    const int qbase = (bid & 7) * 256 + w * 32;

    const ushort_t* Qh = Qp + (size_t)pair * 2048 * 64;
    const ushort_t* Kh = Kp + (size_t)pair * 2048 * 64;
    const ushort_t* Vh = Vtp + (size_t)pair * 64 * 2048;

    // Q B-frags: B[k][col=li] = Q[qbase+li][k], k = ks*16 + hi*8 + j
    bf16x8 qf[4];
#pragma unroll
    for (int ks = 0; ks < 4; ++ks)
        qf[ks] = *(const bf16x8*)&Qh[(size_t)(qbase + li) * 64 + ks * 16 + hi * 8];

    const f32x16 z16 = {0.f,0.f,0.f,0.f,0.f,0.f,0.f,0.f,0.f,0.f,0.f,0.f,0.f,0.f,0.f,0.f};
    f32x16 o0 = z16, o1 = z16;
    float m_ = -1e30f, l_ = 0.f;

    // staging: thread t (0..511) covers row r8 = t>>3 (0..63), slot t&7;
    // writes LDS 16B chunk at slot (t&7)^(r8&7). Read side applies same XOR.
    const int r8 = t >> 3;
    const int lcol = (t & 7) * 16;
    const int swoff = (r8 * 128) + (lcol ^ ((r8 & 7) << 4));
    const char* kp0 = (const char*)Kh + (size_t)r8 * 128 + lcol;   // +8192/tile
    const char* vp0 = (const char*)Vh + (size_t)r8 * 4096 + lcol;  // +128/tile
    char* KsB = (char*)Ks;
    char* VsB = (char*)Vs;
    const int sw = (li & 7) << 4;

    i32x4 gk0 = *(const i32x4*)(kp0);
    i32x4 gv0 = *(const i32x4*)(vp0);
    // prologue: stage tile 0 into buf0, load tile 1 into regs
    *(i32x4*)(KsB + swoff) = gk0;
    *(i32x4*)(VsB + swoff) = gv0;
    gk0 = *(const i32x4*)(kp0 + 8192);
    gv0 = *(const i32x4*)(vp0 + 128);
    __syncthreads();

    for (int it = 0; it < 32; ++it) {
        const int cur = it & 1;
        // stage tile it+1 into buf cur^1 (free: all waves left it after barrier)
        if (it < 31) {
            const int nb = (cur ^ 1) * 8192;
            *(i32x4*)(KsB + nb + swoff) = gk0;
            *(i32x4*)(VsB + nb + swoff) = gv0;
        }
        if (it < 30) {  // issue tile it+2 loads; latency hides under compute
            gk0 = *(const i32x4*)(kp0 + (size_t)(it + 2) * 8192);
            gv0 = *(const i32x4*)(vp0 + (size_t)(it + 2) * 128);
        }

        const char* kb = KsB + cur * 8192;
        const char* vb = VsB + cur * 8192;

        // --- QK^T: S^T[kv][q], two 32-kv halves ---
        f32x16 s0 = z16, s1 = z16;
        __builtin_amdgcn_s_setprio(1);
#pragma unroll
        for (int ks = 0; ks < 4; ++ks) {
            const int b = ks * 32 + hi * 16;
            bf16x8 k0 = *(const bf16x8*)(kb + li * 128 + (b ^ sw));
            bf16x8 k1 = *(const bf16x8*)(kb + (32 + li) * 128 + (b ^ sw));
            s0 = __builtin_amdgcn_mfma_f32_32x32x16_bf16(k0, qf[ks], s0, 0, 0, 0);
            s1 = __builtin_amdgcn_mfma_f32_32x32x16_bf16(k1, qf[ks], s1, 0, 0, 0);
        }
        __builtin_amdgcn_s_setprio(0);

        // --- online softmax (log2 domain), lane-local rows, tree max ---
        float mx[8];
#pragma unroll
        for (int j = 0; j < 8; ++j)
            mx[j] = fmaxf(fmaxf(s0[j], s0[j + 8]), fmaxf(s1[j], s1[j + 8]));
        float m01 = fmaxf(mx[0], mx[1]), m23 = fmaxf(mx[2], mx[3]);
        float m45 = fmaxf(mx[4], mx[5]), m67 = fmaxf(mx[6], mx[7]);
        float tm = fmaxf(fmaxf(m01, m23), fmaxf(m45, m67));
        tm = fmaxf(tm, __shfl_xor(tm, 32));
        if (__any(tm > m_ + 8.f)) {  // defer-max (T13)
            float mn = fmaxf(m_, tm);
            float corr = vexp2(m_ - mn);
#pragma unroll
            for (int r = 0; r < 16; ++r) { o0[r] *= corr; o1[r] *= corr; }
            l_ *= corr;
            m_ = mn;
        }
#pragma unroll
        for (int r = 0; r < 16; ++r) s0[r] = vexp2(s0[r] - m_);
#pragma unroll
        for (int r = 0; r < 16; ++r) s1[r] = vexp2(s1[r] - m_);
        // --- row sum (r6-verified VALU tree) ---
        float su[8];
#pragma unroll
        for (int j = 0; j < 8; ++j)
            su[j] = (s0[j] + s0[j + 8]) + (s1[j] + s1[j + 8]);
        float s01 = su[0] + su[1], s23 = su[2] + su[3];
        float s45 = su[4] + su[5], s67 = su[6] + su[7];
        float sum = (s01 + s23) + (s45 + s67);
        sum += __shfl_xor(sum, 32);
        l_ += sum;

        // --- pack P -> 4 B-frags (verified path) ---
        bf16x8 pf[4];
        pf[0] = mkfrag(s0[0], s0[1], s0[2], s0[3], s0[4], s0[5], s0[6], s0[7], hi);
        pf[1] = mkfrag(s0[8], s0[9], s0[10], s0[11], s0[12], s0[13], s0[14], s0[15], hi);
        pf[2] = mkfrag(s1[0], s1[1], s1[2], s1[3], s1[4], s1[5], s1[6], s1[7], hi);
        pf[3] = mkfrag(s1[8], s1[9], s1[10], s1[11], s1[12], s1[13], s1[14], s1[15], hi);

        // --- PV: O^T[d][q] += V^T . P^T ---
        __builtin_amdgcn_s_setprio(1);
#pragma unroll
        for (int ks = 0; ks < 4; ++ks) {
            const int b = ks * 32 + hi * 16;
            bf16x8 v0 = *(const bf16x8*)(vb + li * 128 + (b ^ sw));
            bf16x8 v1 = *(const bf16x8*)(vb + (32 + li) * 128 + (b ^ sw));
            o0 = __builtin_amdgcn_mfma_f32_32x32x16_bf16(v0, pf[ks], o0, 0, 0, 0);
            o1 = __builtin_amdgcn_mfma_f32_32x32x16_bf16(v1, pf[ks], o1, 0, 0, 0);
        }
        __builtin_amdgcn_s_setprio(0);

        __syncthreads();  // writes to cur^1 visible; everyone done reading cur
    }

    // --- epilogue: lane (li,hi) owns q=qbase+li; o_dt[r] = O^T[d][q],
    //     d = (r&3) + 8*(r>>2) + 4*hi + 32*dt.  l = l_. ---
    const float rl = 1.0f / l_;
    const int b = pair >> 4, hh = pair & 15;
    const int s = qbase + li;
    const size_t rowbase = ((size_t)(b * 2048 + s)) * 1024 + hh * 64;
#pragma unroll
    for (int dt = 0; dt < 2; ++dt) {
#pragma unroll
        for (int rq = 0; rq < 4; ++rq) {
            float v0 = (dt ? o1[rq * 4 + 0] : o0[rq * 4 + 0]) * rl;
            float v1 = (dt ? o1[rq * 4 + 1] : o0[rq * 4 + 1]) * rl;
            float v2 = (dt ? o1[rq * 4 + 2] : o0[rq * 4 + 2]) * rl;
            float v3 = (dt ? o1[rq * 4 + 3] : o0[rq * 4 + 3]) * rl;
            u32x2 uv;
            uv[0] = pkbf(v0, v1);
            uv[1] = pkbf(v2, v3);
            *(u32x2*)&Oa[rowbase + dt * 32 + rq * 8 + hi * 4] = uv;
        }
    }
}

extern "C" void kernel_launch(void* const* d_in, const int* in_sizes, int n_in,
                              void* d_out, int out_size, void* d_ws, size_t ws_size,
                              hipStream_t stream) {
    const float* query = (const float*)d_in[0];
    const float* key_ = (const float*)d_in[1];
    const float* value = (const float*)d_in[2];
    const float* Wq = (const float*)d_in[3];
    const float* bq = (const float*)d_in[4];
    const float* Wk = (const float*)d_in[5];
    const float* bk = (const float*)d_in[6];
    const float* Wv = (const float*)d_in[7];
    const float* bv = (const float*)d_in[8];
    const float* Wo = (const float*)d_in[9];
    const float* bo = (const float*)d_in[10];
    float* out = (float*)d_out;

    char* ws = (char*)d_ws;
    ushort_t* Wqt = (ushort_t*)(ws + 0);
    ushort_t* Wkt = (ushort_t*)(ws + 2097152);
    ushort_t* Wvt = (ushort_t*)(ws + 4194304);
    ushort_t* Wot = (ushort_t*)(ws + 6291456);
    ushort_t* Qp = (ushort_t*)(ws + 8388608);
    ushort_t* Kp = (ushort_t*)(ws + 25165824);
    ushort_t* Vt = (ushort_t*)(ws + 58720256);
    ushort_t* Oa = (ushort_t*)(ws + 41943040);

    transpose_cast4<<<4096, 256, 0, stream>>>(Wq, Wk, Wv, Wo, Wqt, Wkt, Wvt, Wot);

    gemm_qkv<<<1536, 256, 0, stream>>>(query, key_, value, Wqt, Wkt, Wvt,
                                       bq, bk, bv, Qp, Kp, Vt);

    attn_kernel<<<512, 512, 0, stream>>>(Qp, Kp, Vt, Oa);

    gemm_out<<<512, 256, 0, stream>>>(Oa, Wot, bo, out);
}